// Round 10
// baseline (280.675 us; speedup 1.0000x reference)
//
#include <hip/hip_runtime.h>
#include <stdint.h>

typedef unsigned int u32;
typedef unsigned long long u64;

#define N_ANCH 100800
#define NCLS 80
#define ROWF 117
#define KSEL 4096
#define MAXDET 300
#define CONF_T 0.25f
#define IOU_T 0.45f

// workspace layout (bytes)
#define HIST_OFF  0          // u32[8192] — 13-bit first-pass histogram
#define CTL_OFF   32768      // u32[64]: 1:A1 4:B1 6:cnt_gt 7:cnt_eq 8:kept 10:V 32:done
#define ZERO_BYTES 33024
#define SCORE_OFF 33024      // float[N]
#define BUFA_OFF  1645824    // u64[4096]
#define BUFEQ_OFF 1678592    // u64[4096] — full keys of boundary bucket
#define SIDX_OFF  1711360    // u32[4096]
#define SSC_OFF   1727744    // float[4096]
#define BOXES_OFF 1744128    // float4[4096]
#define KEPT_OFF  1809664    // u32[320]
#define MAT_OFF   1811456    // u64[4096*64]
#define WS_NEEDED (MAT_OFF + (size_t)KSEL * 64 * 8)

__device__ __forceinline__ float fsub_rn_(float a, float b) { return __fadd_rn(a, -b); }

__device__ __forceinline__ u64 readlane64_(u64 v, int l) {
  u32 lo = (u32)__builtin_amdgcn_readlane((int)(u32)v, l);
  u32 hi = (u32)__builtin_amdgcn_readlane((int)(u32)(v >> 32), l);
  return ((u64)hi << 32) | lo;
}

__device__ __forceinline__ u64 mx64_(u64 a, u64 b) { return a > b ? a : b; }
__device__ __forceinline__ u64 mn64_(u64 a, u64 b) { return a < b ? a : b; }

// ---- K1: per-row score (16 lanes/row) + 13-bit LDS histogram +
// fused hist-scan in the last-finishing block (done-counter). ----
#define RPB 128  // rows per block
__global__ void __launch_bounds__(256) k_score(const float* __restrict__ pred,
                                               float* __restrict__ score,
                                               u32* __restrict__ hist,
                                               u32* __restrict__ ctl,
                                               int nblocks) {
  __shared__ u32 lh[8192];
  __shared__ u32 partials[256];
  __shared__ u32 prefixs[256];
  __shared__ u32 isLast;
  int t = threadIdx.x;
  for (int q = t; q < 8192; q += 256) lh[q] = 0u;
  __syncthreads();
  int wave = t >> 6, lane = t & 63;
  int g = lane >> 4, j = lane & 15;
  int row0 = blockIdx.x * RPB + wave * (RPB / 4);  // wave covers 32 rows
#pragma unroll
  for (int r = 0; r < RPB / 4; r += 4) {
    int row = row0 + r + g;
    bool ok = row < N_ANCH;
    const float* base = pred + (size_t)(ok ? row : 0) * ROWF;
    float obj = base[4];
    float v0 = base[5 + j], v1 = base[21 + j], v2 = base[37 + j],
          v3 = base[53 + j], v4 = base[69 + j];
    float m = fmaxf(fmaxf(fmaxf(v0, v1), fmaxf(v2, v3)), v4);
    m = fmaxf(m, __shfl_xor(m, 1));
    m = fmaxf(m, __shfl_xor(m, 2));
    m = fmaxf(m, __shfl_xor(m, 4));
    m = fmaxf(m, __shfl_xor(m, 8));
    float sc = (obj > CONF_T) ? __fmul_rn(m, obj) : 0.0f;
    if (ok && j == 0) {
      score[row] = sc;
      atomicAdd(&lh[__float_as_uint(sc) >> 19], 1u);
    }
  }
  __syncthreads();
  for (int q = t; q < 8192; q += 256) {
    u32 c = lh[q];
    if (c) atomicAdd(&hist[q], c);
  }
  // ---- done-counter: last block runs the 8192-bin descending scan ----
  __syncthreads();           // all block atomics issued (compiler drains vmcnt at barrier)
  __threadfence();
  if (t == 0) {
    u32 v = atomicAdd(&ctl[32], 1u);
    isLast = (v == (u32)(nblocks - 1)) ? 1u : 0u;
  }
  __syncthreads();
  if (!isLast) return;
  // last block: re-read hist with L1-bypass (agent-scope) loads
  u32 vals[32];
  int hi = 8192 - 32 * t - 1;  // chunk t covers buckets [hi-31 .. hi], t=0 highest
  u32 s = 0;
#pragma unroll
  for (int q = 0; q < 32; ++q) {
    vals[q] = __hip_atomic_load(&hist[hi - q], __ATOMIC_RELAXED, __HIP_MEMORY_SCOPE_AGENT);
    s += vals[q];
  }
  partials[t] = s;
  __syncthreads();
  if (t == 0) {
    u32 c = 0;
    for (int q = 0; q < 256; ++q) { prefixs[q] = c; c += partials[q]; }
  }
  __syncthreads();
  u32 cum = prefixs[t];
#pragma unroll
  for (int q = 0; q < 32; ++q) {
    u32 h = vals[q];
    if (cum < (u32)KSEL && cum + h >= (u32)KSEL) {
      ctl[4] = (u32)(hi - q);  // B1 (13-bit prefix)
      ctl[1] = cum;            // count strictly above bucket
      break;
    }
    cum += h;
  }
}

// ---- collect: prefix > B1 -> bufA, prefix == B1 -> bufEq (full keys) ----
__global__ void __launch_bounds__(256) k_collect(const float* __restrict__ score,
                                                 u32* __restrict__ ctl,
                                                 u64* __restrict__ bufA,
                                                 u64* __restrict__ bufEq) {
  int i = blockIdx.x * 256 + threadIdx.x;
  int lane = threadIdx.x & 63;
  bool valid = i < N_ANCH;
  u32 key = valid ? __float_as_uint(score[i]) : 0u;
  u32 B = ctl[4];
  u32 pfx = key >> 19;

  bool pg = valid && (pfx > B);
  u64 bg = __ballot(pg);
  u32 baseg = 0;
  if (lane == 0 && bg) baseg = atomicAdd(&ctl[6], (u32)__popcll(bg));
  baseg = __shfl(baseg, 0);
  if (pg) {
    u32 pos = baseg + (u32)__popcll(bg & ((1ull << lane) - 1ull));
    bufA[pos] = ((u64)key << 32) | (u32)(~(u32)i);
  }

  bool pe = valid && (pfx == B);
  u64 be = __ballot(pe);
  u32 basee = 0;
  if (lane == 0 && be) basee = atomicAdd(&ctl[7], (u32)__popcll(be));
  basee = __shfl(basee, 0);
  if (pe) {
    u32 pos = basee + (u32)__popcll(be & ((1ull << lane) - 1ull));
    if (pos < (u32)KSEL) bufEq[pos] = ((u64)key << 32) | (u32)(~(u32)i);
  }
}

// ---- fused: exact boundary select (2-level LDS refine, wave-aggregated
// appends) + register-resident bitonic sort of 4096 u64 keys (descending)
// + epilogue. Wave w owns elements [256w,256w+256): slot s, lane l <->
// (w<<8)|(s<<6)|l. j<=32: shfl_xor. j=64/128: register. j>=256: LDS. ----
__global__ void __launch_bounds__(1024) k_sort(const u64* __restrict__ bufA,
                                               const u64* __restrict__ bufEq,
                                               const float* __restrict__ pred,
                                               u32* __restrict__ sIdx,
                                               float* __restrict__ sScore,
                                               float4* __restrict__ boxes,
                                               u32* __restrict__ ctl) {
  __shared__ u64 a[KSEL];
  __shared__ u64 eq[KSEL];
  __shared__ u64 eqs[512];      // boundary sub-bucket keys (expect ~cnt/256)
  __shared__ u32 h2[256];
  __shared__ u32 selcnt, scnt, b2s, abv2;
  int t = threadIdx.x;
  int w = t >> 6, l = t & 63;

  u32 cgt = ctl[6];                              // count with prefix > B1 (< 4096)
  u32 cnt = ctl[7]; if (cnt > (u32)KSEL) cnt = KSEL;
  u32 need = (u32)KSEL - cgt;                    // 1..4096
  if (t == 0) { selcnt = 0u; scnt = 0u; }
  if (t < 256) h2[t] = 0u;
  for (u32 q = t; q < cnt; q += 1024) eq[q] = bufEq[q];
  __syncthreads();

  if (cnt <= need) {
    // take the whole boundary bucket (cnt == need by construction)
    for (u32 q = t; q < cnt; q += 1024) a[cgt + q] = eq[q];
  } else {
    // level-2: 256-bin histogram of next 8 score bits over the eq set
    for (u32 q = t; q < cnt; q += 1024)
      atomicAdd(&h2[(u32)(eq[q] >> 43) & 0xFFu], 1u);
    __syncthreads();
    // wave 0: descending prefix scan of 256 bins, find sub-bucket B2
    if (w == 0) {
      u32 base = 255u - 4u * (u32)l;  // lane covers bins base..base-3 (descending)
      u32 v0 = h2[base], v1 = h2[base - 1], v2 = h2[base - 2], v3 = h2[base - 3];
      u32 s = v0 + v1 + v2 + v3;
      u32 pre = s;
#pragma unroll
      for (int off = 1; off < 64; off <<= 1) {
        u32 nb = __shfl_up(pre, off, 64);
        if (l >= off) pre += nb;
      }
      u32 c = pre - s;  // count strictly above this lane's group
      u32 vals[4] = {v0, v1, v2, v3};
#pragma unroll
      for (int q = 0; q < 4; ++q) {
        if (c < need && c + vals[q] >= need) { b2s = base - q; abv2 = c; }
        c += vals[q];
      }
    }
    __syncthreads();
    u32 B2 = b2s, need2 = need - abv2;
    // partition (wave-aggregated appends): sub > B2 -> a[]; sub == B2 -> eqs
    for (u32 q = t; q < cnt; q += 1024) {
      u64 x = eq[q];
      u32 sb = (u32)(x >> 43) & 0xFFu;
      bool gg = sb > B2;
      bool e2 = sb == B2;
      u64 bg = __ballot(gg);
      u64 be = __ballot(e2);
      u32 bgb = 0, beb = 0;
      if (l == 0) {
        if (bg) bgb = atomicAdd(&selcnt, (u32)__popcll(bg));
        if (be) beb = atomicAdd(&scnt, (u32)__popcll(be));
      }
      bgb = __shfl(bgb, 0);
      beb = __shfl(beb, 0);
      u64 mk = (1ull << l) - 1ull;
      if (gg) a[cgt + bgb + (u32)__popcll(bg & mk)] = x;
      if (e2) {
        u32 p = beb + (u32)__popcll(be & mk);
        if (p < 512u) eqs[p] = x;
      }
    }
    __syncthreads();
    u32 m = scnt; if (m > 512u) m = 512u;
    for (u32 q = t; q < m; q += 1024) {
      u64 x = eqs[q];
      u32 rank = 0;
      for (u32 j = 0; j < m; ++j) rank += (eqs[j] > x) ? 1u : 0u;
      if (rank < need2) a[cgt + atomicAdd(&selcnt, 1u)] = x;
    }
  }
  __syncthreads();

  // load 4 elements into registers
  u64 e[4];
#pragma unroll
  for (int s = 0; s < 4; ++s) {
    int i = (w << 8) | (s << 6) | l;
    e[s] = ((u32)i < cgt) ? bufA[i] : a[i];
  }
  __syncthreads();  // fill reads done before main sort reuses a[]

  for (int k = 2; k <= KSEL; k <<= 1) {
    // cross-wave phases j >= 256 (wave-uniform direction)
    for (int j = k >> 1; j >= 256; j >>= 1) {
      __syncthreads();
#pragma unroll
      for (int s = 0; s < 4; ++s) a[(w << 8) | (s << 6) | l] = e[s];
      __syncthreads();
      int i0 = (w << 8) | l;
      bool kmax = (((i0 & k) == 0) != ((i0 & j) != 0));
#pragma unroll
      for (int s = 0; s < 4; ++s) {
        u64 p = a[((w << 8) | (s << 6) | l) ^ j];
        e[s] = kmax ? mx64_(e[s], p) : mn64_(e[s], p);
      }
    }
    // j = 128: register pairs (0,2),(1,3)
    if (k >= 256) {
      bool up = ((((w << 8) | l) & k) == 0);
      u64 A, B;
      A = e[0]; B = e[2];
      e[0] = up ? mx64_(A, B) : mn64_(A, B);
      e[2] = up ? mn64_(A, B) : mx64_(A, B);
      A = e[1]; B = e[3];
      e[1] = up ? mx64_(A, B) : mn64_(A, B);
      e[3] = up ? mn64_(A, B) : mx64_(A, B);
    }
    // j = 64: register pairs (0,1),(2,3)
    if (k >= 128) {
      bool upA = ((((w << 8) | (0 << 6) | l) & k) == 0);
      bool upB = ((((w << 8) | (2 << 6) | l) & k) == 0);
      u64 A, B;
      A = e[0]; B = e[1];
      e[0] = upA ? mx64_(A, B) : mn64_(A, B);
      e[1] = upA ? mn64_(A, B) : mx64_(A, B);
      A = e[2]; B = e[3];
      e[2] = upB ? mx64_(A, B) : mn64_(A, B);
      e[3] = upB ? mn64_(A, B) : mx64_(A, B);
    }
    // j <= 32: shuffle phases, no barrier
    for (int j = (k >> 1 < 32 ? k >> 1 : 32); j >= 1; j >>= 1) {
#pragma unroll
      for (int s = 0; s < 4; ++s) {
        u64 p = __shfl_xor(e[s], j, 64);
        int i = (w << 8) | (s << 6) | l;
        bool kmax = (((i & k) == 0) != ((l & j) != 0));
        e[s] = kmax ? mx64_(e[s], p) : mn64_(e[s], p);
      }
    }
  }

  // park sorted keys in LDS for the epilogue
  __syncthreads();
#pragma unroll
  for (int s = 0; s < 4; ++s) a[(w << 8) | (s << 6) | l] = e[s];
  __syncthreads();

  for (int idx = t; idx < KSEL; idx += 1024) {
    u64 kv = a[idx];
    u32 oi = ~((u32)kv);
    float sc = __uint_as_float((u32)(kv >> 32));
    sIdx[idx] = oi;
    sScore[idx] = sc;
    if (sc > 0.0f) {
      bool last = (idx == KSEL - 1);
      float nsc = last ? -1.0f : __uint_as_float((u32)(a[idx + 1] >> 32));
      if (last || nsc <= 0.0f) ctl[10] = (u32)(idx + 1);  // valid count V
    }
    const float* row = pred + (size_t)oi * ROWF;
    float x = row[0], y = row[1], wd = row[2], h = row[3];
    float hw = __fmul_rn(wd, 0.5f), hh = __fmul_rn(h, 0.5f);
    float4 b;
    b.x = fsub_rn_(y, hh);   // y1
    b.y = fsub_rn_(x, hw);   // x1
    b.z = __fadd_rn(y, hh);  // y2
    b.w = __fadd_rn(x, hw);  // x2
    boxes[idx] = b;
  }
}

// ---- IoU suppression bit-matrix: wave = 64 columns, ballot = one word ----
__global__ void __launch_bounds__(256) k_iou(const float4* __restrict__ boxes,
                                             u64* __restrict__ mat) {
  int wave = threadIdx.x >> 6, lane = threadIdx.x & 63;
  int cw = blockIdx.x * 4 + wave;     // word (column-block) index 0..63
  int j = (cw << 6) | lane;           // column 0..4095
  int i0 = blockIdx.y * 128;
  float4 bj = boxes[j];
  float areaJ = __fmul_rn(fsub_rn_(bj.z, bj.x), fsub_rn_(bj.w, bj.y));
  for (int i = i0; i < i0 + 128; ++i) {
    float4 bi = boxes[i];
    float areaI = __fmul_rn(fsub_rn_(bi.z, bi.x), fsub_rn_(bi.w, bi.y));
    float iy1 = fmaxf(bi.x, bj.x);
    float ix1 = fmaxf(bi.y, bj.y);
    float iy2 = fminf(bi.z, bj.z);
    float ix2 = fminf(bi.w, bj.w);
    float dy = fmaxf(fsub_rn_(iy2, iy1), 0.0f);
    float dx = fmaxf(fsub_rn_(ix2, ix1), 0.0f);
    float inter = __fmul_rn(dy, dx);
    float uni = fsub_rn_(__fadd_rn(areaI, areaJ), inter);
    float iou = inter / fmaxf(uni, 1e-9f);
    bool p = (j > i) && (iou > IOU_T);
    u64 m = __ballot(p);
    if (lane == 0) mat[(size_t)i * 64 + cw] = m;
  }
}

// ---- greedy NMS scan: 1 wave, lane owns one 64-bit suppressed word.
// 64-deep unconditional register prefetch ring; diagonal word via readlane
// (scalar) instead of a second load stream; early exit at MAXDET kept. ----
#define NMS_D 64
__global__ void __launch_bounds__(64) k_nms(const u64* __restrict__ mat,
                                            u32* __restrict__ ctl,
                                            u32* __restrict__ kept) {
  int lane = threadIdx.x;
  int V = (int)ctl[10];
  u64 rbuf[NMS_D];
#pragma unroll
  for (int d = 0; d < NMS_D; ++d) {
    int pr = (d < V) ? d : 0;
    rbuf[d] = mat[(size_t)pr * 64 + lane];
  }
  u64 removed = 0ull;
  u64 rw = 0ull;
  int kc = 0;
  bool done = (V == 0);
  for (int i0 = 0; i0 < V; i0 += NMS_D) {
    if (done) break;
#pragma unroll
    for (int d = 0; d < NMS_D; ++d) {
      int i = i0 + d;
      u64 rowv = rbuf[d];
      // unconditional prefetch of row i+NMS_D (clamped; dead value past V)
      int nr = i + NMS_D;
      int pr = (nr < V) ? nr : 0;
      rbuf[d] = mat[(size_t)pr * 64 + lane];
      if (!done && i < V) {
        int w = i >> 6;
        if ((i & 63) == 0) rw = readlane64_(removed, w);
        if (((rw >> (i & 63)) & 1ull) == 0ull) {
          if (lane == 0) kept[kc] = (u32)i;
          removed |= rowv;
          rw |= readlane64_(rowv, w);
          ++kc;
          if (kc == MAXDET) done = true;
        }
      }
    }
  }
  if (lane == 0) ctl[8] = (u32)kc;
}

// ---- output: wave per detection slot ----
__global__ void __launch_bounds__(256) k_out(const float* __restrict__ pred,
                                             const u32* __restrict__ ctl,
                                             const u32* __restrict__ kept,
                                             const u32* __restrict__ sIdx,
                                             const float* __restrict__ sScore,
                                             const float4* __restrict__ boxes,
                                             float* __restrict__ out) {
  int wave = threadIdx.x >> 6, lane = threadIdx.x & 63;
  int s = blockIdx.x * 4 + wave;
  if (s >= MAXDET) return;
  int kc = (int)ctl[8];
  if (s < kc) {
    int pos = (int)kept[s];
    u32 oi = sIdx[pos];
    const float* row = pred + (size_t)oi * ROWF;
    float obj = row[4];
    float v = __fmul_rn(row[5 + lane], obj);
    int ci = lane;
    if (lane < 16) {
      float v2 = __fmul_rn(row[69 + lane], obj);
      if (v2 > v) { v = v2; ci = 64 + lane; }
    }
#pragma unroll
    for (int off = 32; off >= 1; off >>= 1) {
      float ov = __shfl_xor(v, off);
      int oc = __shfl_xor(ci, off);
      if (ov > v || (ov == v && oc < ci)) { v = ov; ci = oc; }
    }
    if (lane == 0) {
      ((float4*)out)[s] = boxes[pos];
      out[1200 + s] = (float)ci;
      out[1500 + s] = sScore[pos];
    }
    if (lane < 32) out[1800 + s * 32 + lane] = row[85 + lane];
  } else {
    if (lane == 0) {
      float4 z = {0.f, 0.f, 0.f, 0.f};
      ((float4*)out)[s] = z;
      out[1200 + s] = 0.f;
      out[1500 + s] = 0.f;
    }
    if (lane < 32) out[1800 + s * 32 + lane] = 0.f;
  }
}

extern "C" void kernel_launch(void* const* d_in, const int* in_sizes, int n_in,
                              void* d_out, int out_size, void* d_ws, size_t ws_size,
                              hipStream_t stream) {
  (void)in_sizes; (void)n_in; (void)out_size;
  if (ws_size < WS_NEEDED) return;  // workspace too small — fail visibly
  const float* pred = (const float*)d_in[0];
  float* out = (float*)d_out;
  char* ws = (char*)d_ws;

  u32* hist = (u32*)(ws + HIST_OFF);
  u32* ctl = (u32*)(ws + CTL_OFF);
  float* score = (float*)(ws + SCORE_OFF);
  u64* bufA = (u64*)(ws + BUFA_OFF);
  u64* bufEq = (u64*)(ws + BUFEQ_OFF);
  u32* sIdx = (u32*)(ws + SIDX_OFF);
  float* sScore = (float*)(ws + SSC_OFF);
  float4* boxes = (float4*)(ws + BOXES_OFF);
  u32* kept = (u32*)(ws + KEPT_OFF);
  u64* mat = (u64*)(ws + MAT_OFF);

  hipMemsetAsync(ws, 0, ZERO_BYTES, stream);

  int nsb = (N_ANCH + RPB - 1) / RPB;
  k_score<<<nsb, 256, 0, stream>>>(pred, score, hist, ctl, nsb);
  int nblk = (N_ANCH + 255) / 256;
  k_collect<<<nblk, 256, 0, stream>>>(score, ctl, bufA, bufEq);
  k_sort<<<1, 1024, 0, stream>>>(bufA, bufEq, pred, sIdx, sScore, boxes, ctl);
  k_iou<<<dim3(16, 32), 256, 0, stream>>>(boxes, mat);
  k_nms<<<1, 64, 0, stream>>>(mat, ctl, kept);
  k_out<<<(MAXDET + 3) / 4, 256, 0, stream>>>(pred, ctl, kept, sIdx, sScore, boxes, out);
}

// Round 12
// 238.432 us; speedup vs baseline: 1.1772x; 1.1772x over previous
//
#include <hip/hip_runtime.h>
#include <stdint.h>

typedef unsigned int u32;
typedef unsigned long long u64;

#define N_ANCH 100800
#define NCLS 80
#define ROWF 117
#define KSEL 4096
#define MAXDET 300
#define CONF_T 0.25f
#define IOU_T 0.45f

// workspace layout (bytes)
#define HIST_OFF  0          // u32[8192] — 13-bit first-pass histogram
#define CTL_OFF   32768      // u32[64]: 1:A1 4:B1 6:cnt_gt 7:cnt_eq 8:kept 10:V
#define ZERO_BYTES 33024
#define SCORE_OFF 33024      // float[N]
#define BUFA_OFF  1645824    // u64[4096]
#define BUFEQ_OFF 1678592    // u64[4096] — full keys of boundary bucket
#define SIDX_OFF  1711360    // u32[4096]
#define SSC_OFF   1727744    // float[4096]
#define BOXES_OFF 1744128    // float4[4096]
#define KEPT_OFF  1809664    // u32[320]
#define MAT_OFF   1811456    // u64[4096*64]
#define WS_NEEDED (MAT_OFF + (size_t)KSEL * 64 * 8)

__device__ __forceinline__ float fsub_rn_(float a, float b) { return __fadd_rn(a, -b); }

__device__ __forceinline__ u64 readlane64_(u64 v, int l) {
  u32 lo = (u32)__builtin_amdgcn_readlane((int)(u32)v, l);
  u32 hi = (u32)__builtin_amdgcn_readlane((int)(u32)(v >> 32), l);
  return ((u64)hi << 32) | lo;
}

__device__ __forceinline__ u64 mx64_(u64 a, u64 b) { return a > b ? a : b; }
__device__ __forceinline__ u64 mn64_(u64 a, u64 b) { return a < b ? a : b; }

// ---- K1: per-row score. 16 lanes per row (4 rows per wave in flight),
// 4-level in-group shfl reduce; multiply-by-obj hoisted past the max
// (rounding is monotonic for fixed positive obj -> bit-identical score).
// 13-bit LDS-privatized histogram. NO done-counter fusion: an agent-scope
// fence per block forces L2 maintenance on non-coherent XCD L2s (round-10
// regression, +50us). ----
#define RPB 128  // rows per block
__global__ void __launch_bounds__(256) k_score(const float* __restrict__ pred,
                                               float* __restrict__ score,
                                               u32* __restrict__ hist) {
  __shared__ u32 lh[8192];
  int t = threadIdx.x;
  for (int q = t; q < 8192; q += 256) lh[q] = 0u;
  __syncthreads();
  int wave = t >> 6, lane = t & 63;
  int g = lane >> 4, j = lane & 15;
  int row0 = blockIdx.x * RPB + wave * (RPB / 4);  // wave covers 32 rows
#pragma unroll
  for (int r = 0; r < RPB / 4; r += 4) {
    int row = row0 + r + g;
    bool ok = row < N_ANCH;
    const float* base = pred + (size_t)(ok ? row : 0) * ROWF;
    float obj = base[4];
    float v0 = base[5 + j], v1 = base[21 + j], v2 = base[37 + j],
          v3 = base[53 + j], v4 = base[69 + j];
    float m = fmaxf(fmaxf(fmaxf(v0, v1), fmaxf(v2, v3)), v4);
    m = fmaxf(m, __shfl_xor(m, 1));
    m = fmaxf(m, __shfl_xor(m, 2));
    m = fmaxf(m, __shfl_xor(m, 4));
    m = fmaxf(m, __shfl_xor(m, 8));
    float sc = (obj > CONF_T) ? __fmul_rn(m, obj) : 0.0f;
    if (ok && j == 0) {
      score[row] = sc;
      atomicAdd(&lh[__float_as_uint(sc) >> 19], 1u);
    }
  }
  __syncthreads();
  for (int q = t; q < 8192; q += 256) {
    u32 c = lh[q];
    if (c) atomicAdd(&hist[q], c);
  }
}

// ---- scan 8192 bins downward: find bucket B1 containing the K-th largest ----
__global__ void __launch_bounds__(256) k_scan(const u32* __restrict__ hist,
                                              u32* __restrict__ ctl) {
  __shared__ u32 partials[256];
  __shared__ u32 prefixs[256];
  int t = threadIdx.x;
  int hi = 8192 - 32 * t - 1;  // chunk t covers buckets [hi-31 .. hi], t=0 highest
  u32 s = 0;
  for (int q = 0; q < 32; ++q) s += hist[hi - q];
  partials[t] = s;
  __syncthreads();
  if (t == 0) {
    u32 c = 0;
    for (int q = 0; q < 256; ++q) { prefixs[q] = c; c += partials[q]; }
  }
  __syncthreads();
  u32 cum = prefixs[t];
  for (int q = 0; q < 32; ++q) {
    u32 h = hist[hi - q];
    if (cum < (u32)KSEL && cum + h >= (u32)KSEL) {
      ctl[4] = (u32)(hi - q);  // B1 (13-bit prefix)
      ctl[1] = cum;            // count strictly above bucket
      break;
    }
    cum += h;
  }
}

// ---- collect: prefix > B1 -> bufA, prefix == B1 -> bufEq (full keys) ----
__global__ void __launch_bounds__(256) k_collect(const float* __restrict__ score,
                                                 u32* __restrict__ ctl,
                                                 u64* __restrict__ bufA,
                                                 u64* __restrict__ bufEq) {
  int i = blockIdx.x * 256 + threadIdx.x;
  int lane = threadIdx.x & 63;
  bool valid = i < N_ANCH;
  u32 key = valid ? __float_as_uint(score[i]) : 0u;
  u32 B = ctl[4];
  u32 pfx = key >> 19;

  bool pg = valid && (pfx > B);
  u64 bg = __ballot(pg);
  u32 baseg = 0;
  if (lane == 0 && bg) baseg = atomicAdd(&ctl[6], (u32)__popcll(bg));
  baseg = __shfl(baseg, 0);
  if (pg) {
    u32 pos = baseg + (u32)__popcll(bg & ((1ull << lane) - 1ull));
    bufA[pos] = ((u64)key << 32) | (u32)(~(u32)i);
  }

  bool pe = valid && (pfx == B);
  u64 be = __ballot(pe);
  u32 basee = 0;
  if (lane == 0 && be) basee = atomicAdd(&ctl[7], (u32)__popcll(be));
  basee = __shfl(basee, 0);
  if (pe) {
    u32 pos = basee + (u32)__popcll(be & ((1ull << lane) - 1ull));
    if (pos < (u32)KSEL) bufEq[pos] = ((u64)key << 32) | (u32)(~(u32)i);
  }
}

// ---- fused: exact boundary select (2-level LDS refine, wave-aggregated
// appends) + register-resident bitonic sort of 4096 u64 keys (descending)
// + epilogue. Wave w owns elements [256w,256w+256): slot s, lane l <->
// (w<<8)|(s<<6)|l. j<=32: shfl_xor. j=64/128: register. j>=256: LDS. ----
__global__ void __launch_bounds__(1024) k_sort(const u64* __restrict__ bufA,
                                               const u64* __restrict__ bufEq,
                                               const float* __restrict__ pred,
                                               u32* __restrict__ sIdx,
                                               float* __restrict__ sScore,
                                               float4* __restrict__ boxes,
                                               u32* __restrict__ ctl) {
  __shared__ u64 a[KSEL];
  __shared__ u64 eq[KSEL];
  __shared__ u64 eqs[512];      // boundary sub-bucket keys (expect ~cnt/256)
  __shared__ u32 h2[256];
  __shared__ u32 selcnt, scnt, b2s, abv2;
  int t = threadIdx.x;
  int w = t >> 6, l = t & 63;

  u32 cgt = ctl[6];                              // count with prefix > B1 (< 4096)
  u32 cnt = ctl[7]; if (cnt > (u32)KSEL) cnt = KSEL;
  u32 need = (u32)KSEL - cgt;                    // 1..4096
  if (t == 0) { selcnt = 0u; scnt = 0u; }
  if (t < 256) h2[t] = 0u;
  for (u32 q = t; q < cnt; q += 1024) eq[q] = bufEq[q];
  __syncthreads();

  if (cnt <= need) {
    // take the whole boundary bucket (cnt == need by construction)
    for (u32 q = t; q < cnt; q += 1024) a[cgt + q] = eq[q];
  } else {
    // level-2: 256-bin histogram of next 8 score bits over the eq set
    for (u32 q = t; q < cnt; q += 1024)
      atomicAdd(&h2[(u32)(eq[q] >> 43) & 0xFFu], 1u);
    __syncthreads();
    // wave 0: descending prefix scan of 256 bins, find sub-bucket B2
    if (w == 0) {
      u32 base = 255u - 4u * (u32)l;  // lane covers bins base..base-3 (descending)
      u32 v0 = h2[base], v1 = h2[base - 1], v2 = h2[base - 2], v3 = h2[base - 3];
      u32 s = v0 + v1 + v2 + v3;
      u32 pre = s;
#pragma unroll
      for (int off = 1; off < 64; off <<= 1) {
        u32 nb = __shfl_up(pre, off, 64);
        if (l >= off) pre += nb;
      }
      u32 c = pre - s;  // count strictly above this lane's group
      u32 vals[4] = {v0, v1, v2, v3};
#pragma unroll
      for (int q = 0; q < 4; ++q) {
        if (c < need && c + vals[q] >= need) { b2s = base - q; abv2 = c; }
        c += vals[q];
      }
    }
    __syncthreads();
    u32 B2 = b2s, need2 = need - abv2;
    // partition (wave-aggregated appends): sub > B2 -> a[]; sub == B2 -> eqs
    for (u32 q = t; q < cnt; q += 1024) {
      u64 x = eq[q];
      u32 sb = (u32)(x >> 43) & 0xFFu;
      bool gg = sb > B2;
      bool e2 = sb == B2;
      u64 bg = __ballot(gg);
      u64 be = __ballot(e2);
      u32 bgb = 0, beb = 0;
      if (l == 0) {
        if (bg) bgb = atomicAdd(&selcnt, (u32)__popcll(bg));
        if (be) beb = atomicAdd(&scnt, (u32)__popcll(be));
      }
      bgb = __shfl(bgb, 0);
      beb = __shfl(beb, 0);
      u64 mk = (1ull << l) - 1ull;
      if (gg) a[cgt + bgb + (u32)__popcll(bg & mk)] = x;
      if (e2) {
        u32 p = beb + (u32)__popcll(be & mk);
        if (p < 512u) eqs[p] = x;
      }
    }
    __syncthreads();
    u32 m = scnt; if (m > 512u) m = 512u;
    for (u32 q = t; q < m; q += 1024) {
      u64 x = eqs[q];
      u32 rank = 0;
      for (u32 j = 0; j < m; ++j) rank += (eqs[j] > x) ? 1u : 0u;
      if (rank < need2) a[cgt + atomicAdd(&selcnt, 1u)] = x;
    }
  }
  __syncthreads();

  // load 4 elements into registers
  u64 e[4];
#pragma unroll
  for (int s = 0; s < 4; ++s) {
    int i = (w << 8) | (s << 6) | l;
    e[s] = ((u32)i < cgt) ? bufA[i] : a[i];
  }
  __syncthreads();  // fill reads done before main sort reuses a[]

  for (int k = 2; k <= KSEL; k <<= 1) {
    // cross-wave phases j >= 256 (wave-uniform direction)
    for (int j = k >> 1; j >= 256; j >>= 1) {
      __syncthreads();
#pragma unroll
      for (int s = 0; s < 4; ++s) a[(w << 8) | (s << 6) | l] = e[s];
      __syncthreads();
      int i0 = (w << 8) | l;
      bool kmax = (((i0 & k) == 0) != ((i0 & j) != 0));
#pragma unroll
      for (int s = 0; s < 4; ++s) {
        u64 p = a[((w << 8) | (s << 6) | l) ^ j];
        e[s] = kmax ? mx64_(e[s], p) : mn64_(e[s], p);
      }
    }
    // j = 128: register pairs (0,2),(1,3)
    if (k >= 256) {
      bool up = ((((w << 8) | l) & k) == 0);
      u64 A, B;
      A = e[0]; B = e[2];
      e[0] = up ? mx64_(A, B) : mn64_(A, B);
      e[2] = up ? mn64_(A, B) : mx64_(A, B);
      A = e[1]; B = e[3];
      e[1] = up ? mx64_(A, B) : mn64_(A, B);
      e[3] = up ? mn64_(A, B) : mx64_(A, B);
    }
    // j = 64: register pairs (0,1),(2,3)
    if (k >= 128) {
      bool upA = ((((w << 8) | (0 << 6) | l) & k) == 0);
      bool upB = ((((w << 8) | (2 << 6) | l) & k) == 0);
      u64 A, B;
      A = e[0]; B = e[1];
      e[0] = upA ? mx64_(A, B) : mn64_(A, B);
      e[1] = upA ? mn64_(A, B) : mx64_(A, B);
      A = e[2]; B = e[3];
      e[2] = upB ? mx64_(A, B) : mn64_(A, B);
      e[3] = upB ? mn64_(A, B) : mx64_(A, B);
    }
    // j <= 32: shuffle phases, no barrier
    for (int j = (k >> 1 < 32 ? k >> 1 : 32); j >= 1; j >>= 1) {
#pragma unroll
      for (int s = 0; s < 4; ++s) {
        u64 p = __shfl_xor(e[s], j, 64);
        int i = (w << 8) | (s << 6) | l;
        bool kmax = (((i & k) == 0) != ((l & j) != 0));
        e[s] = kmax ? mx64_(e[s], p) : mn64_(e[s], p);
      }
    }
  }

  // park sorted keys in LDS for the epilogue
  __syncthreads();
#pragma unroll
  for (int s = 0; s < 4; ++s) a[(w << 8) | (s << 6) | l] = e[s];
  __syncthreads();

  for (int idx = t; idx < KSEL; idx += 1024) {
    u64 kv = a[idx];
    u32 oi = ~((u32)kv);
    float sc = __uint_as_float((u32)(kv >> 32));
    sIdx[idx] = oi;
    sScore[idx] = sc;
    if (sc > 0.0f) {
      bool last = (idx == KSEL - 1);
      float nsc = last ? -1.0f : __uint_as_float((u32)(a[idx + 1] >> 32));
      if (last || nsc <= 0.0f) ctl[10] = (u32)(idx + 1);  // valid count V
    }
    const float* row = pred + (size_t)oi * ROWF;
    float x = row[0], y = row[1], wd = row[2], h = row[3];
    float hw = __fmul_rn(wd, 0.5f), hh = __fmul_rn(h, 0.5f);
    float4 b;
    b.x = fsub_rn_(y, hh);   // y1
    b.y = fsub_rn_(x, hw);   // x1
    b.z = __fadd_rn(y, hh);  // y2
    b.w = __fadd_rn(x, hw);  // x2
    boxes[idx] = b;
  }
}

// ---- IoU suppression bit-matrix: wave = 64 columns, ballot = one word ----
__global__ void __launch_bounds__(256) k_iou(const float4* __restrict__ boxes,
                                             u64* __restrict__ mat) {
  int wave = threadIdx.x >> 6, lane = threadIdx.x & 63;
  int cw = blockIdx.x * 4 + wave;     // word (column-block) index 0..63
  int j = (cw << 6) | lane;           // column 0..4095
  int i0 = blockIdx.y * 128;
  float4 bj = boxes[j];
  float areaJ = __fmul_rn(fsub_rn_(bj.z, bj.x), fsub_rn_(bj.w, bj.y));
  for (int i = i0; i < i0 + 128; ++i) {
    float4 bi = boxes[i];
    float areaI = __fmul_rn(fsub_rn_(bi.z, bi.x), fsub_rn_(bi.w, bi.y));
    float iy1 = fmaxf(bi.x, bj.x);
    float ix1 = fmaxf(bi.y, bj.y);
    float iy2 = fminf(bi.z, bj.z);
    float ix2 = fminf(bi.w, bj.w);
    float dy = fmaxf(fsub_rn_(iy2, iy1), 0.0f);
    float dx = fmaxf(fsub_rn_(ix2, ix1), 0.0f);
    float inter = __fmul_rn(dy, dx);
    float uni = fsub_rn_(__fadd_rn(areaI, areaJ), inter);
    float iou = inter / fmaxf(uni, 1e-9f);
    bool p = (j > i) && (iou > IOU_T);
    u64 m = __ballot(p);
    if (lane == 0) mat[(size_t)i * 64 + cw] = m;
  }
}

// ---- greedy NMS scan: 1 wave, lane owns one 64-bit suppressed word.
// 64-deep unconditional register prefetch ring; diagonal word via readlane
// (scalar) instead of a second load stream; early exit at MAXDET kept. ----
#define NMS_D 64
__global__ void __launch_bounds__(64) k_nms(const u64* __restrict__ mat,
                                            u32* __restrict__ ctl,
                                            u32* __restrict__ kept) {
  int lane = threadIdx.x;
  int V = (int)ctl[10];
  u64 rbuf[NMS_D];
#pragma unroll
  for (int d = 0; d < NMS_D; ++d) {
    int pr = (d < V) ? d : 0;
    rbuf[d] = mat[(size_t)pr * 64 + lane];
  }
  u64 removed = 0ull;
  u64 rw = 0ull;
  int kc = 0;
  bool done = (V == 0);
  for (int i0 = 0; i0 < V; i0 += NMS_D) {
    if (done) break;
#pragma unroll
    for (int d = 0; d < NMS_D; ++d) {
      int i = i0 + d;
      u64 rowv = rbuf[d];
      // unconditional prefetch of row i+NMS_D (clamped; dead value past V)
      int nr = i + NMS_D;
      int pr = (nr < V) ? nr : 0;
      rbuf[d] = mat[(size_t)pr * 64 + lane];
      if (!done && i < V) {
        int w = i >> 6;
        if ((i & 63) == 0) rw = readlane64_(removed, w);
        if (((rw >> (i & 63)) & 1ull) == 0ull) {
          if (lane == 0) kept[kc] = (u32)i;
          removed |= rowv;
          rw |= readlane64_(rowv, w);
          ++kc;
          if (kc == MAXDET) done = true;
        }
      }
    }
  }
  if (lane == 0) ctl[8] = (u32)kc;
}

// ---- output: wave per detection slot ----
__global__ void __launch_bounds__(256) k_out(const float* __restrict__ pred,
                                             const u32* __restrict__ ctl,
                                             const u32* __restrict__ kept,
                                             const u32* __restrict__ sIdx,
                                             const float* __restrict__ sScore,
                                             const float4* __restrict__ boxes,
                                             float* __restrict__ out) {
  int wave = threadIdx.x >> 6, lane = threadIdx.x & 63;
  int s = blockIdx.x * 4 + wave;
  if (s >= MAXDET) return;
  int kc = (int)ctl[8];
  if (s < kc) {
    int pos = (int)kept[s];
    u32 oi = sIdx[pos];
    const float* row = pred + (size_t)oi * ROWF;
    float obj = row[4];
    float v = __fmul_rn(row[5 + lane], obj);
    int ci = lane;
    if (lane < 16) {
      float v2 = __fmul_rn(row[69 + lane], obj);
      if (v2 > v) { v = v2; ci = 64 + lane; }
    }
#pragma unroll
    for (int off = 32; off >= 1; off >>= 1) {
      float ov = __shfl_xor(v, off);
      int oc = __shfl_xor(ci, off);
      if (ov > v || (ov == v && oc < ci)) { v = ov; ci = oc; }
    }
    if (lane == 0) {
      ((float4*)out)[s] = boxes[pos];
      out[1200 + s] = (float)ci;
      out[1500 + s] = sScore[pos];
    }
    if (lane < 32) out[1800 + s * 32 + lane] = row[85 + lane];
  } else {
    if (lane == 0) {
      float4 z = {0.f, 0.f, 0.f, 0.f};
      ((float4*)out)[s] = z;
      out[1200 + s] = 0.f;
      out[1500 + s] = 0.f;
    }
    if (lane < 32) out[1800 + s * 32 + lane] = 0.f;
  }
}

extern "C" void kernel_launch(void* const* d_in, const int* in_sizes, int n_in,
                              void* d_out, int out_size, void* d_ws, size_t ws_size,
                              hipStream_t stream) {
  (void)in_sizes; (void)n_in; (void)out_size;
  if (ws_size < WS_NEEDED) return;  // workspace too small — fail visibly
  const float* pred = (const float*)d_in[0];
  float* out = (float*)d_out;
  char* ws = (char*)d_ws;

  u32* hist = (u32*)(ws + HIST_OFF);
  u32* ctl = (u32*)(ws + CTL_OFF);
  float* score = (float*)(ws + SCORE_OFF);
  u64* bufA = (u64*)(ws + BUFA_OFF);
  u64* bufEq = (u64*)(ws + BUFEQ_OFF);
  u32* sIdx = (u32*)(ws + SIDX_OFF);
  float* sScore = (float*)(ws + SSC_OFF);
  float4* boxes = (float4*)(ws + BOXES_OFF);
  u32* kept = (u32*)(ws + KEPT_OFF);
  u64* mat = (u64*)(ws + MAT_OFF);

  hipMemsetAsync(ws, 0, ZERO_BYTES, stream);

  k_score<<<(N_ANCH + RPB - 1) / RPB, 256, 0, stream>>>(pred, score, hist);
  k_scan<<<1, 256, 0, stream>>>(hist, ctl);
  int nblk = (N_ANCH + 255) / 256;
  k_collect<<<nblk, 256, 0, stream>>>(score, ctl, bufA, bufEq);
  k_sort<<<1, 1024, 0, stream>>>(bufA, bufEq, pred, sIdx, sScore, boxes, ctl);
  k_iou<<<dim3(16, 32), 256, 0, stream>>>(boxes, mat);
  k_nms<<<1, 64, 0, stream>>>(mat, ctl, kept);
  k_out<<<(MAXDET + 3) / 4, 256, 0, stream>>>(pred, ctl, kept, sIdx, sScore, boxes, out);
}